// Round 14
// baseline (145.538 us; speedup 1.0000x reference)
//
#include <hip/hip_runtime.h>
#include <hip/hip_bf16.h>
#include <stdint.h>
#include <stddef.h>

typedef unsigned short u16;
typedef unsigned int   u32;
typedef __attribute__((ext_vector_type(8))) short bf16x8;  // 8 bf16 = 4 VGPRs
typedef __attribute__((ext_vector_type(4))) float f32x4;   // MFMA C/D

#define LOG2E   1.44269504f
#define EXP_OFF 23.0831206f   // 16 * log2(e)

static __device__ __forceinline__ float bf2f(u16 v) {
    u32 u = ((u32)v) << 16; float f; __builtin_memcpy(&f, &u, 4); return f;
}
static __device__ __forceinline__ u16 f2bf(float f) {
    u32 u; __builtin_memcpy(&u, &f, 4);
    u32 r = (u + 0x7fffu + ((u >> 16) & 1u)) >> 16; return (u16)r;
}
static __device__ __forceinline__ float as_f(u32 u) { float f; __builtin_memcpy(&f, &u, 4); return f; }
static __device__ __forceinline__ u32   as_u(float f) { u32 u; __builtin_memcpy(&u, &f, 4); return u; }

// fp32-vs-bf16 input detection (wave 0)
static __device__ __forceinline__ int detect_f32_wave0(const void* x, int t) {
    const u32* xw = (const u32*)x;
    int bad = 0;
    #pragma unroll
    for (int k = 0; k < 4; ++k) {
        u32 wv = xw[(t << 2) + k];
        int e = (wv >> 7) & 0xff;
        bad += (e >= 160);
    }
    unsigned long long m = __ballot(bad > 0);
    return (__popcll(m) >= 8) ? 1 : 0;
}

// V workspace layout (pre-fragmented for MFMA B-operand, per batch):
//   elem_addr = cblk*65536 + jblk*512 + (quad4*16 + clo)*8 + jlo
//   where c = cblk*16 + clo, j = jblk*32 + quad4*8 + jlo.
// A wave B-frag load (lane = quad*16+n16 reads 16B) is 1KB fully contiguous.

// ---------------------------------------------------------------------------
// Kernel 1 (MFMA proj v2): 4 och-groups of 80 (16 q|k rows + 64 V rows).
//   Grid = 64it x 4g x 4n = 1024 blocks = EXACTLY 4/CU (LDS 4x40KB = 160KB
//   exact) -> single scheduling round (was 1280 blocks = 2 rounds, second
//   20% full). x slice re-read x4 instead of x5. Same MFMA layouts,
//   staging swizzle, and output formats as the R1-verified kernel.
// ---------------------------------------------------------------------------
__global__ __launch_bounds__(256) void qkv_proj_mfma(
    const void* __restrict__ x,
    const void* __restrict__ Wq, const void* __restrict__ bq,
    const void* __restrict__ Wk, const void* __restrict__ bk,
    const void* __restrict__ Wv, const void* __restrict__ bv,
    u16* __restrict__ qws, u16* __restrict__ kws, u16* __restrict__ vws,
    int n_off, int nshiftp)
{
    __shared__ u16 Wl[80 * 256];   // 40 KB, swizzled bf16 W-slice (80 rows)
    __shared__ int dtf;

    const int t    = threadIdx.x;
    const int bid  = blockIdx.x;
    const int n_w  = bid & ((1 << nshiftp) - 1);
    const int rest = bid >> nshiftp;
    const int g    = rest & 3;        // och-group: 16 q|k rows + 64 V rows
    const int it   = rest >> 2;       // i-tile (64 i), 0..63
    const int n_g  = n_off + n_w;
    const int i0   = it << 6;

    if (t < 64) { int f = detect_f32_wave0(x, t); if (t == 0) dtf = f; }
    __syncthreads();
    const bool isf32 = (dtf != 0);

    // ---- stage W slice (80 rows x 256 cols) into LDS, swizzled bf16 ----
    // rows 0..15  -> q|k och = g*16 + row  (och<32: Wq, else Wk[och-32])
    // rows 16..79 -> Wv[g*64 + row - 16]
    #pragma unroll
    for (int k = 0; k < 20; ++k) {
        int idx  = t + (k << 8);        // 0..5119
        int row  = idx >> 6;            // 0..79
        int col4 = (idx & 63) << 2;     // 0..252 step 4
        const void* src; int srow;
        if (row < 16) {
            int oqk = (g << 4) + row;
            if (oqk < 32) { src = Wq; srow = oqk; }
            else          { src = Wk; srow = oqk - 32; }
        } else { src = Wv; srow = (g << 6) + row - 16; }
        ushort4 h;
        if (isf32) {
            float4 wv = *((const float4*)((const float*)src + srow * 256 + col4));
            h.x = f2bf(wv.x); h.y = f2bf(wv.y); h.z = f2bf(wv.z); h.w = f2bf(wv.w);
        } else {
            h = *((const ushort4*)((const u16*)src + srow * 256 + col4));
        }
        *(ushort4*)&Wl[(row << 8) + (col4 ^ ((row & 7) << 3))] = h;
    }
    __syncthreads();

    const int lane = t & 63;
    const int w    = t >> 6;          // wave -> i-frag
    const int n16  = lane & 15;
    const int quad = lane >> 4;
    const int i_b  = i0 + (w << 4);
    const int i    = i_b + n16;
    const int swz  = (n16 & 7) << 3;

    f32x4 acc[5];
    #pragma unroll
    for (int f = 0; f < 5; ++f) acc[f] = (f32x4){0.f, 0.f, 0.f, 0.f};

    // ---- k-loop: 8 chunks of 32 c; A direct-global, B from LDS ----
    if (isf32) {
        const float* xp = (const float*)x
            + (((size_t)(n_g * 256 + (quad << 3))) << 12) + i;
        float af[8];
        #pragma unroll
        for (int e = 0; e < 8; ++e) af[e] = xp[(size_t)e << 12];
        #pragma unroll
        for (int c8 = 0; c8 < 8; ++c8) {
            bf16x8 a;
            #pragma unroll
            for (int e = 0; e < 8; ++e) a[e] = (short)f2bf(af[e]);
            if (c8 < 7) {
                const float* xn = xp + (((size_t)(c8 + 1) << 5) << 12);
                #pragma unroll
                for (int e = 0; e < 8; ++e) af[e] = xn[(size_t)e << 12];
            }
            const int c0 = c8 << 5;
            #pragma unroll
            for (int f = 0; f < 5; ++f) {
                const int brow = (f << 4) + n16;
                bf16x8 b = *(const bf16x8*)
                    &Wl[(brow << 8) + ((c0 + (quad << 3)) ^ swz)];
                acc[f] = __builtin_amdgcn_mfma_f32_16x16x32_bf16(a, b, acc[f], 0, 0, 0);
            }
        }
    } else {
        const u16* xp = (const u16*)x
            + (((size_t)(n_g * 256 + (quad << 3))) << 12) + i;
        u16 af[8];
        #pragma unroll
        for (int e = 0; e < 8; ++e) af[e] = xp[(size_t)e << 12];
        #pragma unroll
        for (int c8 = 0; c8 < 8; ++c8) {
            bf16x8 a;
            #pragma unroll
            for (int e = 0; e < 8; ++e) a[e] = (short)af[e];
            if (c8 < 7) {
                const u16* xn = xp + (((size_t)(c8 + 1) << 5) << 12);
                #pragma unroll
                for (int e = 0; e < 8; ++e) af[e] = xn[(size_t)e << 12];
            }
            const int c0 = c8 << 5;
            #pragma unroll
            for (int f = 0; f < 5; ++f) {
                const int brow = (f << 4) + n16;
                bf16x8 b = *(const bf16x8*)
                    &Wl[(brow << 8) + ((c0 + (quad << 3)) ^ swz)];
                acc[f] = __builtin_amdgcn_mfma_f32_16x16x32_bf16(a, b, acc[f], 0, 0, 0);
            }
        }
    }

    // ---- epilogue: D frag (col = n16 = och-local, row = quad*4+r = i) ----
    // f = 0: q|k och = g*16 + n16.  f = 1..4: V c = g*64 + (f-1)*16 + n16.
    {
        const int och = (g << 4) + n16;      // f = 0 (q|k)
        const bool isq = (och < 32);
        float bias;
        if (isf32) bias = ((const float*)(isq ? bq : bk))[isq ? och : (och - 32)];
        else       bias = bf2f(((const u16*)(isq ? bq : bk))[isq ? och : (och - 32)]);
        u16* dst = (isq ? qws : kws) + (((size_t)n_w) << 17) + (isq ? och : (och - 32));
        const float scale = isq ? LOG2E : 1.0f;
        #pragma unroll
        for (int r = 0; r < 4; ++r) {
            const int ii = i_b + (quad << 2) + r;
            dst[(size_t)ii << 5] = f2bf((acc[0][r] + bias) * scale);
        }
    }
    #pragma unroll
    for (int f = 1; f < 5; ++f) {
        const int c = (g << 6) + ((f - 1) << 4) + n16;   // c&15 == n16
        float bias = isf32 ? ((const float*)bv)[c]
                           : bf2f(((const u16*)bv)[c]);
        const int i4 = i_b + (quad << 2);
        ushort4 h;
        h.x = f2bf(acc[f][0] + bias);
        h.y = f2bf(acc[f][1] + bias);
        h.z = f2bf(acc[f][2] + bias);
        h.w = f2bf(acc[f][3] + bias);
        const size_t addr = ((size_t)n_w << 20)
            + ((size_t)(c >> 4) << 16)          // cblk*65536
            + ((size_t)(i4 >> 5) << 9)          // jblk*512
            + (size_t)((((((i4 & 31) >> 3) << 4) + (c & 15)) << 3) + (i4 & 7));
        *(ushort4*)(vws + addr) = h;
    }
}

// ---------------------------------------------------------------------------
// Kernel 2 (v18, unchanged — measured best 51.6us at R13): swapped-S^T with
// packed b64 P-write, b128 P-reads, K phase-start dbuf, V next-phase consume.
// ---------------------------------------------------------------------------
__global__ __launch_bounds__(1024) void flash_mfma15(
    const u16* __restrict__ qws, const u16* __restrict__ kws,
    const u16* __restrict__ vws, void* __restrict__ out,
    const void* __restrict__ x, int n_off, int nshift)
{
    __shared__ __align__(16) char arena[17920];
    __shared__ __align__(16) float lS[64];
    __shared__ int dtf;
    char*  PsA  = arena;                 // + par*8192 bytes
    float* Dbuf = (float*)arena;         // epilogue alias

    const int t    = threadIdx.x;
    const int lane = t & 63;
    const int w    = t >> 6;          // 0..15
    const int n16  = lane & 15;
    const int quad = lane >> 4;
    const int bid  = blockIdx.x;
    const int n_w  = bid & ((1 << nshift) - 1);
    const int qt   = bid >> nshift;
    const int n_g  = n_off + n_w;
    const int i0   = qt << 6;

    if (t < 64) {
        int f = detect_f32_wave0(x, t);
        if (t == 0) dtf = f;
        lS[t] = 0.f;
    }

    const u16* qb = qws + (((size_t)n_w) << 17);
    const u16* kb = kws + (((size_t)n_w) << 17);
    const u16* vb = vws + (((size_t)n_w) << 20);

    // S decomposition (operand loads as v9; MFMA argument order swapped)
    const int qsub_s = w & 3;
    const int jsub   = w >> 2;
    // PV decomposition: 32 c x 32 j per wave (v9)
    const int cq = w & 7;
    const int jq = w >> 3;

    const bf16x8 qfrag =
        *(const bf16x8*)(qb + ((size_t)(i0 + (qsub_s << 4) + n16) << 5) + (quad << 3));

    f32x4 acc[4][2];
    #pragma unroll
    for (int a = 0; a < 4; ++a)
        #pragma unroll
        for (int b = 0; b < 2; ++b) acc[a][b] = (f32x4){0.f, 0.f, 0.f, 0.f};
    float lps = 0.f;   // single running sum (lane q = n16)

    const f32x4 zoff = {-EXP_OFF, -EXP_OFF, -EXP_OFF, -EXP_OFF};

    // P byte layout: byte(q,j) = q*128 + ((2j) ^ ((q&7)<<4))
    const int pwoff = ((qsub_s << 4) + n16) * 128 +
                      (((jsub << 5) + (quad << 3)) ^ ((n16 & 7) << 4));
    int paoff[4];
    #pragma unroll
    for (int qs = 0; qs < 4; ++qs)
        paoff[qs] = ((qs << 4) + n16) * 128 +
                    (((jq << 6) + (quad << 4)) ^ ((n16 & 7) << 4));

    // K frag pointer: K(T) at kp + T*2048 elems (lane row = j)
    const u16* kp = kb + ((size_t)((jsub << 4) + n16) << 5) + (quad << 3);
    // Pre-fragmented V base: cblk = cq*2 (+1 for second frag), jblk = tile*2+jq
    const u16* vfp0 = vb + ((size_t)(cq << 1) << 16) + ((size_t)jq << 9)
                         + ((size_t)((quad << 4) + n16) << 3);
    const u16* vfp1 = vfp0 + 65536;

    bf16x8 kcur, knext, vf0, vf1;

    // ---- prologue: S^T(0) into parity 0; prefetch K(1), V-frags for PV(0) ----
    kcur = *(const bf16x8*)(kp);
    {
        f32x4 s = __builtin_amdgcn_mfma_f32_16x16x32_bf16(kcur, qfrag, zoff, 0, 0, 0);
        float p0 = exp2f(s[0]); u32 u0 = as_u(p0) & 0xffff0000u; lps += as_f(u0);
        float p1 = exp2f(s[1]); u32 u1 = as_u(p1) & 0xffff0000u; lps += as_f(u1);
        float p2 = exp2f(s[2]); u32 u2 = as_u(p2) & 0xffff0000u; lps += as_f(u2);
        float p3 = exp2f(s[3]); u32 u3 = as_u(p3) & 0xffff0000u; lps += as_f(u3);
        uint2 pw;
        pw.x = (u0 >> 16) | (u1 & 0xffff0000u);
        pw.y = (u2 >> 16) | (u3 & 0xffff0000u);
        *(uint2*)(PsA + pwoff) = pw;
        knext = *(const bf16x8*)(kp + 2048);
        vf0 = *(const bf16x8*)(vfp0);
        vf1 = *(const bf16x8*)(vfp1);
    }
    __syncthreads();

    // ---- main loop: ONE barrier per tile; vmem issued at phase start ----
    for (int tile = 1; tile < 64; ++tile) {
        const int par = tile & 1;
        char* Psc = PsA + (par << 13);
        char* Psp = PsA + ((par ^ 1) << 13);

        kcur = knext;
        if (tile < 63) {
            knext = *(const bf16x8*)(kp + ((size_t)(tile + 1) << 11));
        }

        // PV(tile-1): pa from LDS, vf from prefetched coalesced global regs
        bf16x8 pa[4];
        #pragma unroll
        for (int qs = 0; qs < 4; ++qs)
            pa[qs] = *(const bf16x8*)(Psp + paoff[qs]);
        #pragma unroll
        for (int qs = 0; qs < 4; ++qs) {
            acc[qs][0] = __builtin_amdgcn_mfma_f32_16x16x32_bf16(pa[qs], vf0, acc[qs][0], 0, 0, 0);
            acc[qs][1] = __builtin_amdgcn_mfma_f32_16x16x32_bf16(pa[qs], vf1, acc[qs][1], 0, 0, 0);
        }

        // prefetch V-frags for PV(tile) (consumed next phase, as v9)
        vf0 = *(const bf16x8*)(vfp0 + ((size_t)tile << 10));
        vf1 = *(const bf16x8*)(vfp1 + ((size_t)tile << 10));

        // S^T(tile) + softmax + packed b64 P write (kcur loaded one phase ago)
        f32x4 s = __builtin_amdgcn_mfma_f32_16x16x32_bf16(kcur, qfrag, zoff, 0, 0, 0);
        float p0 = exp2f(s[0]); u32 u0 = as_u(p0) & 0xffff0000u; lps += as_f(u0);
        float p1 = exp2f(s[1]); u32 u1 = as_u(p1) & 0xffff0000u; lps += as_f(u1);
        float p2 = exp2f(s[2]); u32 u2 = as_u(p2) & 0xffff0000u; lps += as_f(u2);
        float p3 = exp2f(s[3]); u32 u3 = as_u(p3) & 0xffff0000u; lps += as_f(u3);
        uint2 pw;
        pw.x = (u0 >> 16) | (u1 & 0xffff0000u);
        pw.y = (u2 >> 16) | (u3 & 0xffff0000u);
        *(uint2*)(Psc + pwoff) = pw;

        __syncthreads();
    }

    // ---- final PV(63): parity 1, vf holds jblk of tile 63 ----
    {
        char* Psp = PsA + 8192;
        bf16x8 pa[4];
        #pragma unroll
        for (int qs = 0; qs < 4; ++qs)
            pa[qs] = *(const bf16x8*)(Psp + paoff[qs]);
        #pragma unroll
        for (int qs = 0; qs < 4; ++qs) {
            acc[qs][0] = __builtin_amdgcn_mfma_f32_16x16x32_bf16(pa[qs], vf0, acc[qs][0], 0, 0, 0);
            acc[qs][1] = __builtin_amdgcn_mfma_f32_16x16x32_bf16(pa[qs], vf1, acc[qs][1], 0, 0, 0);
        }
    }

    // ---- l reduction: sum over quads (xor 16, 32), then per-q atomic ----
    lps += __shfl_xor(lps, 16);
    lps += __shfl_xor(lps, 32);
    if (lane < 16) atomicAdd(&lS[(qsub_s << 4) + lane], lps);
    __syncthreads();
    if (t < 64) lS[t] = 1.0f / lS[t];
    const bool isf32 = (dtf != 0);

    // ---- epilogue: 4 chunks of 64 c; combine jq-partials in Dbuf, store ----
    for (int chunk = 0; chunk < 4; ++chunk) {
        __syncthreads();   // Dbuf free; rl ready; Ps reads complete (chunk 0)
        if (jq == 1 && (cq >> 1) == chunk) {
            #pragma unroll
            for (int qs = 0; qs < 4; ++qs)
                #pragma unroll
                for (int cs = 0; cs < 2; ++cs)
                    *(f32x4*)&Dbuf[(((cq & 1) << 5) + (cs << 4) + n16) * 68 +
                                   (qs << 4) + (quad << 2)] = acc[qs][cs];
        }
        __syncthreads();
        if (jq == 0 && (cq >> 1) == chunk) {
            #pragma unroll
            for (int qs = 0; qs < 4; ++qs)
                #pragma unroll
                for (int cs = 0; cs < 2; ++cs) {
                    float* p = &Dbuf[(((cq & 1) << 5) + (cs << 4) + n16) * 68 +
                                     (qs << 4) + (quad << 2)];
                    f32x4 d = *(f32x4*)p;
                    d += acc[qs][cs];
                    *(f32x4*)p = d;
                }
        }
        __syncthreads();
        // store: 1024 threads x 4 q
        const int c_l = t >> 4;
        const int qg  = (t & 15) << 2;
        float4 d  = *(float4*)&Dbuf[c_l * 68 + qg];
        float4 rl = *(float4*)&lS[qg];
        const int c_glob = (chunk << 6) + c_l;
        const size_t ob = (((size_t)(n_g * 256 + c_glob)) << 12) + i0 + qg;
        if (isf32) {
            float4 o = make_float4(d.x * rl.x, d.y * rl.y, d.z * rl.z, d.w * rl.w);
            *(float4*)((float*)out + ob) = o;
        } else {
            union { uint2 v; u16 h[4]; } o;
            o.h[0] = f2bf(d.x * rl.x);
            o.h[1] = f2bf(d.y * rl.y);
            o.h[2] = f2bf(d.z * rl.z);
            o.h[3] = f2bf(d.w * rl.w);
            *(uint2*)((u16*)out + ob) = o.v;
        }
    }
}

extern "C" void kernel_launch(void* const* d_in, const int* in_sizes, int n_in,
                              void* d_out, int out_size, void* d_ws, size_t ws_size,
                              hipStream_t stream)
{
    const void* x  = d_in[0];
    const void* Wq = d_in[1];
    const void* bq = d_in[2];
    const void* Wk = d_in[3];
    const void* bk = d_in[4];
    const void* Wv = d_in[5];
    const void* bv = d_in[6];

    const size_t full_need = (size_t)(4u * 4096u) * (32 + 32 + 256) * 2; // 10 MB
    if (ws_size >= full_need) {
        u16* qws = (u16*)d_ws;
        u16* kws = qws + (size_t)4 * 4096 * 32;
        u16* vws = kws + (size_t)4 * 4096 * 32;
        // proj grid = ((it*4 + g)*4) + n : 64 it x 4 och-groups x 4 batches
        qkv_proj_mfma<<<dim3(1024), dim3(256), 0, stream>>>(
            x, Wq, bq, Wk, bk, Wv, bv, qws, kws, vws, 0, 2);
        flash_mfma15<<<dim3(256), dim3(1024), 0, stream>>>(
            qws, kws, vws, d_out, x, 0, 2);
    } else {
        u16* qws = (u16*)d_ws;
        u16* kws = qws + (size_t)4096 * 32;
        u16* vws = kws + (size_t)4096 * 32;
        for (int n = 0; n < 4; ++n) {
            qkv_proj_mfma<<<dim3(256), dim3(256), 0, stream>>>(
                x, Wq, bq, Wk, bk, Wv, bv, qws, kws, vws, n, 0);
            flash_mfma15<<<dim3(64), dim3(1024), 0, stream>>>(
                qws, kws, vws, d_out, x, n, 0);
        }
    }
}

// Round 15
// 143.748 us; speedup vs baseline: 1.0125x; 1.0125x over previous
//
#include <hip/hip_runtime.h>
#include <hip/hip_bf16.h>
#include <stdint.h>
#include <stddef.h>

typedef unsigned short u16;
typedef unsigned int   u32;
typedef __attribute__((ext_vector_type(8))) short bf16x8;  // 8 bf16 = 4 VGPRs
typedef __attribute__((ext_vector_type(4))) float f32x4;   // MFMA C/D

#define LOG2E   1.44269504f
#define EXP_OFF 23.0831206f   // 16 * log2(e)

static __device__ __forceinline__ float bf2f(u16 v) {
    u32 u = ((u32)v) << 16; float f; __builtin_memcpy(&f, &u, 4); return f;
}
static __device__ __forceinline__ u16 f2bf(float f) {
    u32 u; __builtin_memcpy(&u, &f, 4);
    u32 r = (u + 0x7fffu + ((u >> 16) & 1u)) >> 16; return (u16)r;
}
static __device__ __forceinline__ float as_f(u32 u) { float f; __builtin_memcpy(&f, &u, 4); return f; }
static __device__ __forceinline__ u32   as_u(float f) { u32 u; __builtin_memcpy(&u, &f, 4); return u; }

// In-loop barrier: drain LDS ops only (ds_write visibility), leave vector
// loads in flight across the barrier (register K/V prefetches need no
// cross-wave visibility). __syncthreads() would emit vmcnt(0) and forfeit
// the prefetch cover every tile.
static __device__ __forceinline__ void barrier_lds_only() {
    asm volatile("s_waitcnt lgkmcnt(0)" ::: "memory");
    __builtin_amdgcn_s_barrier();
}

// fp32-vs-bf16 input detection (wave 0)
static __device__ __forceinline__ int detect_f32_wave0(const void* x, int t) {
    const u32* xw = (const u32*)x;
    int bad = 0;
    #pragma unroll
    for (int k = 0; k < 4; ++k) {
        u32 wv = xw[(t << 2) + k];
        int e = (wv >> 7) & 0xff;
        bad += (e >= 160);
    }
    unsigned long long m = __ballot(bad > 0);
    return (__popcll(m) >= 8) ? 1 : 0;
}

// V workspace layout (pre-fragmented for MFMA B-operand, per batch):
//   elem_addr = cblk*65536 + jblk*512 + (quad4*16 + clo)*8 + jlo
//   where c = cblk*16 + clo, j = jblk*32 + quad4*8 + jlo.
// A wave B-frag load (lane = quad*16+n16 reads 16B) is 1KB fully contiguous.

// ---------------------------------------------------------------------------
// Kernel 1 (MFMA proj, R1-verified version — R14's re-grid was neutral,
// reverted):
// ---------------------------------------------------------------------------
__global__ __launch_bounds__(256) void qkv_proj_mfma(
    const void* __restrict__ x,
    const void* __restrict__ Wq, const void* __restrict__ bq,
    const void* __restrict__ Wk, const void* __restrict__ bk,
    const void* __restrict__ Wv, const void* __restrict__ bv,
    u16* __restrict__ qws, u16* __restrict__ kws, u16* __restrict__ vws,
    int n_off, int nshiftp)
{
    __shared__ u16 Wl[64 * 256];   // 32 KB, swizzled bf16 W-slice
    __shared__ int dtf;

    const int t    = threadIdx.x;
    const int bid  = blockIdx.x;
    const int n_w  = bid & ((1 << nshiftp) - 1);
    const int rest = bid >> nshiftp;
    const int g    = rest % 5;        // 0 = q+k, 1..4 = v quarters
    const int it   = rest / 5;        // i-tile (64 i)
    const int n_g  = n_off + n_w;
    const int i0   = it << 6;

    if (t < 64) { int f = detect_f32_wave0(x, t); if (t == 0) dtf = f; }
    __syncthreads();
    const bool isf32 = (dtf != 0);

    // ---- stage W slice (64 rows x 256 cols) into LDS, swizzled bf16 ----
    #pragma unroll
    for (int k = 0; k < 16; ++k) {
        int idx  = t + (k << 8);
        int row  = idx >> 6;            // 0..63 (wave-uniform per k)
        int col4 = (idx & 63) << 2;     // 0..252 step 4
        const void* src; int srow;
        if (g == 0) {
            if (row < 32) { src = Wq; srow = row; }
            else          { src = Wk; srow = row - 32; }
        } else { src = Wv; srow = ((g - 1) << 6) + row; }
        ushort4 h;
        if (isf32) {
            float4 wv = *((const float4*)((const float*)src + srow * 256 + col4));
            h.x = f2bf(wv.x); h.y = f2bf(wv.y); h.z = f2bf(wv.z); h.w = f2bf(wv.w);
        } else {
            h = *((const ushort4*)((const u16*)src + srow * 256 + col4));
        }
        *(ushort4*)&Wl[(row << 8) + (col4 ^ ((row & 7) << 3))] = h;
    }
    __syncthreads();

    const int lane = t & 63;
    const int w    = t >> 6;          // wave -> i-frag
    const int n16  = lane & 15;
    const int quad = lane >> 4;
    const int i_b  = i0 + (w << 4);
    const int i    = i_b + n16;
    const int swz  = (n16 & 7) << 3;

    f32x4 acc[4];
    #pragma unroll
    for (int f = 0; f < 4; ++f) acc[f] = (f32x4){0.f, 0.f, 0.f, 0.f};

    // ---- k-loop: 8 chunks of 32 c; A direct-global, B from LDS ----
    if (isf32) {
        const float* xp = (const float*)x
            + (((size_t)(n_g * 256 + (quad << 3))) << 12) + i;
        float af[8];
        #pragma unroll
        for (int e = 0; e < 8; ++e) af[e] = xp[(size_t)e << 12];
        #pragma unroll
        for (int c8 = 0; c8 < 8; ++c8) {
            bf16x8 a;
            #pragma unroll
            for (int e = 0; e < 8; ++e) a[e] = (short)f2bf(af[e]);
            if (c8 < 7) {
                const float* xn = xp + (((size_t)(c8 + 1) << 5) << 12);
                #pragma unroll
                for (int e = 0; e < 8; ++e) af[e] = xn[(size_t)e << 12];
            }
            const int c0 = c8 << 5;
            #pragma unroll
            for (int f = 0; f < 4; ++f) {
                const int brow = (f << 4) + n16;
                bf16x8 b = *(const bf16x8*)
                    &Wl[(brow << 8) + ((c0 + (quad << 3)) ^ swz)];
                acc[f] = __builtin_amdgcn_mfma_f32_16x16x32_bf16(a, b, acc[f], 0, 0, 0);
            }
        }
    } else {
        const u16* xp = (const u16*)x
            + (((size_t)(n_g * 256 + (quad << 3))) << 12) + i;
        u16 af[8];
        #pragma unroll
        for (int e = 0; e < 8; ++e) af[e] = xp[(size_t)e << 12];
        #pragma unroll
        for (int c8 = 0; c8 < 8; ++c8) {
            bf16x8 a;
            #pragma unroll
            for (int e = 0; e < 8; ++e) a[e] = (short)af[e];
            if (c8 < 7) {
                const u16* xn = xp + (((size_t)(c8 + 1) << 5) << 12);
                #pragma unroll
                for (int e = 0; e < 8; ++e) af[e] = xn[(size_t)e << 12];
            }
            const int c0 = c8 << 5;
            #pragma unroll
            for (int f = 0; f < 4; ++f) {
                const int brow = (f << 4) + n16;
                bf16x8 b = *(const bf16x8*)
                    &Wl[(brow << 8) + ((c0 + (quad << 3)) ^ swz)];
                acc[f] = __builtin_amdgcn_mfma_f32_16x16x32_bf16(a, b, acc[f], 0, 0, 0);
            }
        }
    }

    // ---- epilogue: D frag is (col = n16 = och-local, row = quad*4+r = i) ----
    if (g == 0) {
        #pragma unroll
        for (int f = 0; f < 4; ++f) {
            const int ol   = (f << 4) + n16;     // 0..63
            const bool isq = (ol < 32);
            const int och  = isq ? ol : (ol - 32);
            float bias;
            if (isf32) bias = ((const float*)(isq ? bq : bk))[och];
            else       bias = bf2f(((const u16*)(isq ? bq : bk))[och]);
            u16* dst = (isq ? qws : kws) + (((size_t)n_w) << 17) + och;
            const float scale = isq ? LOG2E : 1.0f;
            #pragma unroll
            for (int r = 0; r < 4; ++r) {
                const int ii = i_b + (quad << 2) + r;
                dst[(size_t)ii << 5] = f2bf((acc[f][r] + bias) * scale);
            }
        }
    } else {
        #pragma unroll
        for (int f = 0; f < 4; ++f) {
            const int c = ((g - 1) << 6) + (f << 4) + n16;   // c&15 == n16
            float bias = isf32 ? ((const float*)bv)[c]
                               : bf2f(((const u16*)bv)[c]);
            const int i4 = i_b + (quad << 2);
            ushort4 h;
            h.x = f2bf(acc[f][0] + bias);
            h.y = f2bf(acc[f][1] + bias);
            h.z = f2bf(acc[f][2] + bias);
            h.w = f2bf(acc[f][3] + bias);
            const size_t addr = ((size_t)n_w << 20)
                + ((size_t)(c >> 4) << 16)          // cblk*65536
                + ((size_t)(i4 >> 5) << 9)          // jblk*512
                + (size_t)((((((i4 & 31) >> 3) << 4) + (c & 15)) << 3) + (i4 & 7));
            *(ushort4*)(vws + addr) = h;
        }
    }
}

// ---------------------------------------------------------------------------
// Kernel 2 (v19): flash_mfma15 (51.6us, R13-proven) with ONE change —
// in-loop __syncthreads() replaced by barrier_lds_only() (lgkmcnt(0) +
// raw s_barrier). __syncthreads emits vmcnt(0) at every barrier, draining
// the K/V REGISTER prefetches that need no cross-wave visibility — the
// phase pays its own loads' L2 latency every tile. With the LDS-only
// drain, prefetches genuinely span barriers (compiler inserts counted
// vmcnt(N) before the consuming MFMA). Epilogue keeps __syncthreads.
// ---------------------------------------------------------------------------
__global__ __launch_bounds__(1024) void flash_mfma16(
    const u16* __restrict__ qws, const u16* __restrict__ kws,
    const u16* __restrict__ vws, void* __restrict__ out,
    const void* __restrict__ x, int n_off, int nshift)
{
    __shared__ __align__(16) char arena[17920];
    __shared__ __align__(16) float lS[64];
    __shared__ int dtf;
    char*  PsA  = arena;                 // + par*8192 bytes
    float* Dbuf = (float*)arena;         // epilogue alias

    const int t    = threadIdx.x;
    const int lane = t & 63;
    const int w    = t >> 6;          // 0..15
    const int n16  = lane & 15;
    const int quad = lane >> 4;
    const int bid  = blockIdx.x;
    const int n_w  = bid & ((1 << nshift) - 1);
    const int qt   = bid >> nshift;
    const int n_g  = n_off + n_w;
    const int i0   = qt << 6;

    if (t < 64) {
        int f = detect_f32_wave0(x, t);
        if (t == 0) dtf = f;
        lS[t] = 0.f;
    }

    const u16* qb = qws + (((size_t)n_w) << 17);
    const u16* kb = kws + (((size_t)n_w) << 17);
    const u16* vb = vws + (((size_t)n_w) << 20);

    // S decomposition (operand loads as v9; MFMA argument order swapped)
    const int qsub_s = w & 3;
    const int jsub   = w >> 2;
    // PV decomposition: 32 c x 32 j per wave (v9)
    const int cq = w & 7;
    const int jq = w >> 3;

    const bf16x8 qfrag =
        *(const bf16x8*)(qb + ((size_t)(i0 + (qsub_s << 4) + n16) << 5) + (quad << 3));

    f32x4 acc[4][2];
    #pragma unroll
    for (int a = 0; a < 4; ++a)
        #pragma unroll
        for (int b = 0; b < 2; ++b) acc[a][b] = (f32x4){0.f, 0.f, 0.f, 0.f};
    float lps = 0.f;   // single running sum (lane q = n16)

    const f32x4 zoff = {-EXP_OFF, -EXP_OFF, -EXP_OFF, -EXP_OFF};

    // P byte layout: byte(q,j) = q*128 + ((2j) ^ ((q&7)<<4))
    const int pwoff = ((qsub_s << 4) + n16) * 128 +
                      (((jsub << 5) + (quad << 3)) ^ ((n16 & 7) << 4));
    int paoff[4];
    #pragma unroll
    for (int qs = 0; qs < 4; ++qs)
        paoff[qs] = ((qs << 4) + n16) * 128 +
                    (((jq << 6) + (quad << 4)) ^ ((n16 & 7) << 4));

    // K frag pointer: K(T) at kp + T*2048 elems (lane row = j)
    const u16* kp = kb + ((size_t)((jsub << 4) + n16) << 5) + (quad << 3);
    // Pre-fragmented V base: cblk = cq*2 (+1 for second frag), jblk = tile*2+jq
    const u16* vfp0 = vb + ((size_t)(cq << 1) << 16) + ((size_t)jq << 9)
                         + ((size_t)((quad << 4) + n16) << 3);
    const u16* vfp1 = vfp0 + 65536;

    bf16x8 kcur, knext, vf0, vf1;

    // ---- prologue: S^T(0) into parity 0; prefetch K(1), V-frags for PV(0) ----
    kcur = *(const bf16x8*)(kp);
    {
        f32x4 s = __builtin_amdgcn_mfma_f32_16x16x32_bf16(kcur, qfrag, zoff, 0, 0, 0);
        float p0 = exp2f(s[0]); u32 u0 = as_u(p0) & 0xffff0000u; lps += as_f(u0);
        float p1 = exp2f(s[1]); u32 u1 = as_u(p1) & 0xffff0000u; lps += as_f(u1);
        float p2 = exp2f(s[2]); u32 u2 = as_u(p2) & 0xffff0000u; lps += as_f(u2);
        float p3 = exp2f(s[3]); u32 u3 = as_u(p3) & 0xffff0000u; lps += as_f(u3);
        uint2 pw;
        pw.x = (u0 >> 16) | (u1 & 0xffff0000u);
        pw.y = (u2 >> 16) | (u3 & 0xffff0000u);
        *(uint2*)(PsA + pwoff) = pw;
        knext = *(const bf16x8*)(kp + 2048);
        vf0 = *(const bf16x8*)(vfp0);
        vf1 = *(const bf16x8*)(vfp1);
    }
    barrier_lds_only();

    // ---- main loop: ONE lds-only barrier per tile; loads span barriers ----
    for (int tile = 1; tile < 64; ++tile) {
        const int par = tile & 1;
        char* Psc = PsA + (par << 13);
        char* Psp = PsA + ((par ^ 1) << 13);

        kcur = knext;
        if (tile < 63) {
            knext = *(const bf16x8*)(kp + ((size_t)(tile + 1) << 11));
        }

        // PV(tile-1): pa from LDS, vf from prefetched coalesced global regs
        bf16x8 pa[4];
        #pragma unroll
        for (int qs = 0; qs < 4; ++qs)
            pa[qs] = *(const bf16x8*)(Psp + paoff[qs]);
        #pragma unroll
        for (int qs = 0; qs < 4; ++qs) {
            acc[qs][0] = __builtin_amdgcn_mfma_f32_16x16x32_bf16(pa[qs], vf0, acc[qs][0], 0, 0, 0);
            acc[qs][1] = __builtin_amdgcn_mfma_f32_16x16x32_bf16(pa[qs], vf1, acc[qs][1], 0, 0, 0);
        }

        // prefetch V-frags for PV(tile) (consumed next phase)
        vf0 = *(const bf16x8*)(vfp0 + ((size_t)tile << 10));
        vf1 = *(const bf16x8*)(vfp1 + ((size_t)tile << 10));

        // S^T(tile) + softmax + packed b64 P write (kcur loaded one phase ago)
        f32x4 s = __builtin_amdgcn_mfma_f32_16x16x32_bf16(kcur, qfrag, zoff, 0, 0, 0);
        float p0 = exp2f(s[0]); u32 u0 = as_u(p0) & 0xffff0000u; lps += as_f(u0);
        float p1 = exp2f(s[1]); u32 u1 = as_u(p1) & 0xffff0000u; lps += as_f(u1);
        float p2 = exp2f(s[2]); u32 u2 = as_u(p2) & 0xffff0000u; lps += as_f(u2);
        float p3 = exp2f(s[3]); u32 u3 = as_u(p3) & 0xffff0000u; lps += as_f(u3);
        uint2 pw;
        pw.x = (u0 >> 16) | (u1 & 0xffff0000u);
        pw.y = (u2 >> 16) | (u3 & 0xffff0000u);
        *(uint2*)(Psc + pwoff) = pw;

        barrier_lds_only();
    }

    // ---- final PV(63): parity 1, vf holds jblk of tile 63 ----
    {
        char* Psp = PsA + 8192;
        bf16x8 pa[4];
        #pragma unroll
        for (int qs = 0; qs < 4; ++qs)
            pa[qs] = *(const bf16x8*)(Psp + paoff[qs]);
        #pragma unroll
        for (int qs = 0; qs < 4; ++qs) {
            acc[qs][0] = __builtin_amdgcn_mfma_f32_16x16x32_bf16(pa[qs], vf0, acc[qs][0], 0, 0, 0);
            acc[qs][1] = __builtin_amdgcn_mfma_f32_16x16x32_bf16(pa[qs], vf1, acc[qs][1], 0, 0, 0);
        }
    }

    // ---- l reduction: sum over quads (xor 16, 32), then per-q atomic ----
    lps += __shfl_xor(lps, 16);
    lps += __shfl_xor(lps, 32);
    if (lane < 16) atomicAdd(&lS[(qsub_s << 4) + lane], lps);
    __syncthreads();
    if (t < 64) lS[t] = 1.0f / lS[t];
    const bool isf32 = (dtf != 0);

    // ---- epilogue: 4 chunks of 64 c; combine jq-partials in Dbuf, store ----
    for (int chunk = 0; chunk < 4; ++chunk) {
        __syncthreads();   // Dbuf free; rl ready; Ps reads complete (chunk 0)
        if (jq == 1 && (cq >> 1) == chunk) {
            #pragma unroll
            for (int qs = 0; qs < 4; ++qs)
                #pragma unroll
                for (int cs = 0; cs < 2; ++cs)
                    *(f32x4*)&Dbuf[(((cq & 1) << 5) + (cs << 4) + n16) * 68 +
                                   (qs << 4) + (quad << 2)] = acc[qs][cs];
        }
        __syncthreads();
        if (jq == 0 && (cq >> 1) == chunk) {
            #pragma unroll
            for (int qs = 0; qs < 4; ++qs)
                #pragma unroll
                for (int cs = 0; cs < 2; ++cs) {
                    float* p = &Dbuf[(((cq & 1) << 5) + (cs << 4) + n16) * 68 +
                                     (qs << 4) + (quad << 2)];
                    f32x4 d = *(f32x4*)p;
                    d += acc[qs][cs];
                    *(f32x4*)p = d;
                }
        }
        __syncthreads();
        // store: 1024 threads x 4 q
        const int c_l = t >> 4;
        const int qg  = (t & 15) << 2;
        float4 d  = *(float4*)&Dbuf[c_l * 68 + qg];
        float4 rl = *(float4*)&lS[qg];
        const int c_glob = (chunk << 6) + c_l;
        const size_t ob = (((size_t)(n_g * 256 + c_glob)) << 12) + i0 + qg;
        if (isf32) {
            float4 o = make_float4(d.x * rl.x, d.y * rl.y, d.z * rl.z, d.w * rl.w);
            *(float4*)((float*)out + ob) = o;
        } else {
            union { uint2 v; u16 h[4]; } o;
            o.h[0] = f2bf(d.x * rl.x);
            o.h[1] = f2bf(d.y * rl.y);
            o.h[2] = f2bf(d.z * rl.z);
            o.h[3] = f2bf(d.w * rl.w);
            *(uint2*)((u16*)out + ob) = o.v;
        }
    }
}

extern "C" void kernel_launch(void* const* d_in, const int* in_sizes, int n_in,
                              void* d_out, int out_size, void* d_ws, size_t ws_size,
                              hipStream_t stream)
{
    const void* x  = d_in[0];
    const void* Wq = d_in[1];
    const void* bq = d_in[2];
    const void* Wk = d_in[3];
    const void* bk = d_in[4];
    const void* Wv = d_in[5];
    const void* bv = d_in[6];

    const size_t full_need = (size_t)(4u * 4096u) * (32 + 32 + 256) * 2; // 10 MB
    if (ws_size >= full_need) {
        u16* qws = (u16*)d_ws;
        u16* kws = qws + (size_t)4 * 4096 * 32;
        u16* vws = kws + (size_t)4 * 4096 * 32;
        qkv_proj_mfma<<<dim3(1280), dim3(256), 0, stream>>>(
            x, Wq, bq, Wk, bk, Wv, bv, qws, kws, vws, 0, 2);
        flash_mfma16<<<dim3(256), dim3(1024), 0, stream>>>(
            qws, kws, vws, d_out, x, 0, 2);
    } else {
        u16* qws = (u16*)d_ws;
        u16* kws = qws + (size_t)4096 * 32;
        u16* vws = kws + (size_t)4096 * 32;
        for (int n = 0; n < 4; ++n) {
            qkv_proj_mfma<<<dim3(320), dim3(256), 0, stream>>>(
                x, Wq, bq, Wk, bk, Wv, bv, qws, kws, vws, n, 0);
            flash_mfma16<<<dim3(64), dim3(1024), 0, stream>>>(
                qws, kws, vws, d_out, x, n, 0);
        }
    }
}

// Round 16
// 141.576 us; speedup vs baseline: 1.0280x; 1.0153x over previous
//
#include <hip/hip_runtime.h>
#include <hip/hip_bf16.h>
#include <stdint.h>
#include <stddef.h>

typedef unsigned short u16;
typedef unsigned int   u32;
typedef __attribute__((ext_vector_type(8))) short bf16x8;  // 8 bf16 = 4 VGPRs
typedef __attribute__((ext_vector_type(4))) float f32x4;   // MFMA C/D

#define LOG2E   1.44269504f
#define EXP_OFF 23.0831206f   // 16 * log2(e)

static __device__ __forceinline__ float bf2f(u16 v) {
    u32 u = ((u32)v) << 16; float f; __builtin_memcpy(&f, &u, 4); return f;
}
static __device__ __forceinline__ u16 f2bf(float f) {
    u32 u; __builtin_memcpy(&u, &f, 4);
    u32 r = (u + 0x7fffu + ((u >> 16) & 1u)) >> 16; return (u16)r;
}
static __device__ __forceinline__ float as_f(u32 u) { float f; __builtin_memcpy(&f, &u, 4); return f; }
static __device__ __forceinline__ u32   as_u(float f) { u32 u; __builtin_memcpy(&u, &f, 4); return u; }

// In-loop barrier: drain LDS ops only (ds_write visibility), leave vector
// loads in flight across the barrier (register K/V prefetches need no
// cross-wave visibility). __syncthreads() would emit vmcnt(0) and forfeit
// the prefetch cover every tile. (R15: measured −0.7us vs __syncthreads.)
static __device__ __forceinline__ void barrier_lds_only() {
    asm volatile("s_waitcnt lgkmcnt(0)" ::: "memory");
    __builtin_amdgcn_s_barrier();
}

// fp32-vs-bf16 input detection (wave 0)
static __device__ __forceinline__ int detect_f32_wave0(const void* x, int t) {
    const u32* xw = (const u32*)x;
    int bad = 0;
    #pragma unroll
    for (int k = 0; k < 4; ++k) {
        u32 wv = xw[(t << 2) + k];
        int e = (wv >> 7) & 0xff;
        bad += (e >= 160);
    }
    unsigned long long m = __ballot(bad > 0);
    return (__popcll(m) >= 8) ? 1 : 0;
}

// V workspace layout (pre-fragmented for MFMA B-operand, per batch):
//   elem_addr = cblk*65536 + jblk*512 + (quad4*16 + clo)*8 + jlo
//   where c = cblk*16 + clo, j = jblk*32 + quad4*8 + jlo.
// A wave B-frag load (lane = quad*16+n16 reads 16B) is 1KB fully contiguous.

// ---------------------------------------------------------------------------
// Kernel 1 (MFMA proj, R1-verified version):
// ---------------------------------------------------------------------------
__global__ __launch_bounds__(256) void qkv_proj_mfma(
    const void* __restrict__ x,
    const void* __restrict__ Wq, const void* __restrict__ bq,
    const void* __restrict__ Wk, const void* __restrict__ bk,
    const void* __restrict__ Wv, const void* __restrict__ bv,
    u16* __restrict__ qws, u16* __restrict__ kws, u16* __restrict__ vws,
    int n_off, int nshiftp)
{
    __shared__ u16 Wl[64 * 256];   // 32 KB, swizzled bf16 W-slice
    __shared__ int dtf;

    const int t    = threadIdx.x;
    const int bid  = blockIdx.x;
    const int n_w  = bid & ((1 << nshiftp) - 1);
    const int rest = bid >> nshiftp;
    const int g    = rest % 5;        // 0 = q+k, 1..4 = v quarters
    const int it   = rest / 5;        // i-tile (64 i)
    const int n_g  = n_off + n_w;
    const int i0   = it << 6;

    if (t < 64) { int f = detect_f32_wave0(x, t); if (t == 0) dtf = f; }
    __syncthreads();
    const bool isf32 = (dtf != 0);

    // ---- stage W slice (64 rows x 256 cols) into LDS, swizzled bf16 ----
    #pragma unroll
    for (int k = 0; k < 16; ++k) {
        int idx  = t + (k << 8);
        int row  = idx >> 6;            // 0..63 (wave-uniform per k)
        int col4 = (idx & 63) << 2;     // 0..252 step 4
        const void* src; int srow;
        if (g == 0) {
            if (row < 32) { src = Wq; srow = row; }
            else          { src = Wk; srow = row - 32; }
        } else { src = Wv; srow = ((g - 1) << 6) + row; }
        ushort4 h;
        if (isf32) {
            float4 wv = *((const float4*)((const float*)src + srow * 256 + col4));
            h.x = f2bf(wv.x); h.y = f2bf(wv.y); h.z = f2bf(wv.z); h.w = f2bf(wv.w);
        } else {
            h = *((const ushort4*)((const u16*)src + srow * 256 + col4));
        }
        *(ushort4*)&Wl[(row << 8) + (col4 ^ ((row & 7) << 3))] = h;
    }
    __syncthreads();

    const int lane = t & 63;
    const int w    = t >> 6;          // wave -> i-frag
    const int n16  = lane & 15;
    const int quad = lane >> 4;
    const int i_b  = i0 + (w << 4);
    const int i    = i_b + n16;
    const int swz  = (n16 & 7) << 3;

    f32x4 acc[4];
    #pragma unroll
    for (int f = 0; f < 4; ++f) acc[f] = (f32x4){0.f, 0.f, 0.f, 0.f};

    // ---- k-loop: 8 chunks of 32 c; A direct-global, B from LDS ----
    if (isf32) {
        const float* xp = (const float*)x
            + (((size_t)(n_g * 256 + (quad << 3))) << 12) + i;
        float af[8];
        #pragma unroll
        for (int e = 0; e < 8; ++e) af[e] = xp[(size_t)e << 12];
        #pragma unroll
        for (int c8 = 0; c8 < 8; ++c8) {
            bf16x8 a;
            #pragma unroll
            for (int e = 0; e < 8; ++e) a[e] = (short)f2bf(af[e]);
            if (c8 < 7) {
                const float* xn = xp + (((size_t)(c8 + 1) << 5) << 12);
                #pragma unroll
                for (int e = 0; e < 8; ++e) af[e] = xn[(size_t)e << 12];
            }
            const int c0 = c8 << 5;
            #pragma unroll
            for (int f = 0; f < 4; ++f) {
                const int brow = (f << 4) + n16;
                bf16x8 b = *(const bf16x8*)
                    &Wl[(brow << 8) + ((c0 + (quad << 3)) ^ swz)];
                acc[f] = __builtin_amdgcn_mfma_f32_16x16x32_bf16(a, b, acc[f], 0, 0, 0);
            }
        }
    } else {
        const u16* xp = (const u16*)x
            + (((size_t)(n_g * 256 + (quad << 3))) << 12) + i;
        u16 af[8];
        #pragma unroll
        for (int e = 0; e < 8; ++e) af[e] = xp[(size_t)e << 12];
        #pragma unroll
        for (int c8 = 0; c8 < 8; ++c8) {
            bf16x8 a;
            #pragma unroll
            for (int e = 0; e < 8; ++e) a[e] = (short)af[e];
            if (c8 < 7) {
                const u16* xn = xp + (((size_t)(c8 + 1) << 5) << 12);
                #pragma unroll
                for (int e = 0; e < 8; ++e) af[e] = xn[(size_t)e << 12];
            }
            const int c0 = c8 << 5;
            #pragma unroll
            for (int f = 0; f < 4; ++f) {
                const int brow = (f << 4) + n16;
                bf16x8 b = *(const bf16x8*)
                    &Wl[(brow << 8) + ((c0 + (quad << 3)) ^ swz)];
                acc[f] = __builtin_amdgcn_mfma_f32_16x16x32_bf16(a, b, acc[f], 0, 0, 0);
            }
        }
    }

    // ---- epilogue: D frag is (col = n16 = och-local, row = quad*4+r = i) ----
    if (g == 0) {
        #pragma unroll
        for (int f = 0; f < 4; ++f) {
            const int ol   = (f << 4) + n16;     // 0..63
            const bool isq = (ol < 32);
            const int och  = isq ? ol : (ol - 32);
            float bias;
            if (isf32) bias = ((const float*)(isq ? bq : bk))[och];
            else       bias = bf2f(((const u16*)(isq ? bq : bk))[och]);
            u16* dst = (isq ? qws : kws) + (((size_t)n_w) << 17) + och;
            const float scale = isq ? LOG2E : 1.0f;
            #pragma unroll
            for (int r = 0; r < 4; ++r) {
                const int ii = i_b + (quad << 2) + r;
                dst[(size_t)ii << 5] = f2bf((acc[f][r] + bias) * scale);
            }
        }
    } else {
        #pragma unroll
        for (int f = 0; f < 4; ++f) {
            const int c = ((g - 1) << 6) + (f << 4) + n16;   // c&15 == n16
            float bias = isf32 ? ((const float*)bv)[c]
                               : bf2f(((const u16*)bv)[c]);
            const int i4 = i_b + (quad << 2);
            ushort4 h;
            h.x = f2bf(acc[f][0] + bias);
            h.y = f2bf(acc[f][1] + bias);
            h.z = f2bf(acc[f][2] + bias);
            h.w = f2bf(acc[f][3] + bias);
            const size_t addr = ((size_t)n_w << 20)
                + ((size_t)(c >> 4) << 16)          // cblk*65536
                + ((size_t)(i4 >> 5) << 9)          // jblk*512
                + (size_t)((((((i4 & 31) >> 3) << 4) + (c & 15)) << 3) + (i4 & 7));
            *(ushort4*)(vws + addr) = h;
        }
    }
}

// ---------------------------------------------------------------------------
// Kernel 2 (v20): v19 (51.0us, R15-proven) + s_setprio(1) around the 9-MFMA
// cluster (PV x8 + S x1). With the LDS-only barrier, waves drift within a
// phase (loads no longer drain at barriers), creating the role diversity
// T5 needs: MFMA-entering waves get issue priority over load-issuing waves.
// Everything else byte-identical to v19.
// ---------------------------------------------------------------------------
__global__ __launch_bounds__(1024) void flash_mfma17(
    const u16* __restrict__ qws, const u16* __restrict__ kws,
    const u16* __restrict__ vws, void* __restrict__ out,
    const void* __restrict__ x, int n_off, int nshift)
{
    __shared__ __align__(16) char arena[17920];
    __shared__ __align__(16) float lS[64];
    __shared__ int dtf;
    char*  PsA  = arena;                 // + par*8192 bytes
    float* Dbuf = (float*)arena;         // epilogue alias

    const int t    = threadIdx.x;
    const int lane = t & 63;
    const int w    = t >> 6;          // 0..15
    const int n16  = lane & 15;
    const int quad = lane >> 4;
    const int bid  = blockIdx.x;
    const int n_w  = bid & ((1 << nshift) - 1);
    const int qt   = bid >> nshift;
    const int n_g  = n_off + n_w;
    const int i0   = qt << 6;

    if (t < 64) {
        int f = detect_f32_wave0(x, t);
        if (t == 0) dtf = f;
        lS[t] = 0.f;
    }

    const u16* qb = qws + (((size_t)n_w) << 17);
    const u16* kb = kws + (((size_t)n_w) << 17);
    const u16* vb = vws + (((size_t)n_w) << 20);

    // S decomposition (operand loads as v9; MFMA argument order swapped)
    const int qsub_s = w & 3;
    const int jsub   = w >> 2;
    // PV decomposition: 32 c x 32 j per wave (v9)
    const int cq = w & 7;
    const int jq = w >> 3;

    const bf16x8 qfrag =
        *(const bf16x8*)(qb + ((size_t)(i0 + (qsub_s << 4) + n16) << 5) + (quad << 3));

    f32x4 acc[4][2];
    #pragma unroll
    for (int a = 0; a < 4; ++a)
        #pragma unroll
        for (int b = 0; b < 2; ++b) acc[a][b] = (f32x4){0.f, 0.f, 0.f, 0.f};
    float lps = 0.f;   // single running sum (lane q = n16)

    const f32x4 zoff = {-EXP_OFF, -EXP_OFF, -EXP_OFF, -EXP_OFF};

    // P byte layout: byte(q,j) = q*128 + ((2j) ^ ((q&7)<<4))
    const int pwoff = ((qsub_s << 4) + n16) * 128 +
                      (((jsub << 5) + (quad << 3)) ^ ((n16 & 7) << 4));
    int paoff[4];
    #pragma unroll
    for (int qs = 0; qs < 4; ++qs)
        paoff[qs] = ((qs << 4) + n16) * 128 +
                    (((jq << 6) + (quad << 4)) ^ ((n16 & 7) << 4));

    // K frag pointer: K(T) at kp + T*2048 elems (lane row = j)
    const u16* kp = kb + ((size_t)((jsub << 4) + n16) << 5) + (quad << 3);
    // Pre-fragmented V base: cblk = cq*2 (+1 for second frag), jblk = tile*2+jq
    const u16* vfp0 = vb + ((size_t)(cq << 1) << 16) + ((size_t)jq << 9)
                         + ((size_t)((quad << 4) + n16) << 3);
    const u16* vfp1 = vfp0 + 65536;

    bf16x8 kcur, knext, vf0, vf1;

    // ---- prologue: S^T(0) into parity 0; prefetch K(1), V-frags for PV(0) ----
    kcur = *(const bf16x8*)(kp);
    {
        f32x4 s = __builtin_amdgcn_mfma_f32_16x16x32_bf16(kcur, qfrag, zoff, 0, 0, 0);
        float p0 = exp2f(s[0]); u32 u0 = as_u(p0) & 0xffff0000u; lps += as_f(u0);
        float p1 = exp2f(s[1]); u32 u1 = as_u(p1) & 0xffff0000u; lps += as_f(u1);
        float p2 = exp2f(s[2]); u32 u2 = as_u(p2) & 0xffff0000u; lps += as_f(u2);
        float p3 = exp2f(s[3]); u32 u3 = as_u(p3) & 0xffff0000u; lps += as_f(u3);
        uint2 pw;
        pw.x = (u0 >> 16) | (u1 & 0xffff0000u);
        pw.y = (u2 >> 16) | (u3 & 0xffff0000u);
        *(uint2*)(PsA + pwoff) = pw;
        knext = *(const bf16x8*)(kp + 2048);
        vf0 = *(const bf16x8*)(vfp0);
        vf1 = *(const bf16x8*)(vfp1);
    }
    barrier_lds_only();

    // ---- main loop: ONE lds-only barrier per tile; loads span barriers ----
    for (int tile = 1; tile < 64; ++tile) {
        const int par = tile & 1;
        char* Psc = PsA + (par << 13);
        char* Psp = PsA + ((par ^ 1) << 13);

        kcur = knext;
        if (tile < 63) {
            knext = *(const bf16x8*)(kp + ((size_t)(tile + 1) << 11));
        }

        // PV(tile-1): pa from LDS, vf from prefetched coalesced global regs
        bf16x8 pa[4];
        #pragma unroll
        for (int qs = 0; qs < 4; ++qs)
            pa[qs] = *(const bf16x8*)(Psp + paoff[qs]);

        __builtin_amdgcn_s_setprio(1);
        #pragma unroll
        for (int qs = 0; qs < 4; ++qs) {
            acc[qs][0] = __builtin_amdgcn_mfma_f32_16x16x32_bf16(pa[qs], vf0, acc[qs][0], 0, 0, 0);
            acc[qs][1] = __builtin_amdgcn_mfma_f32_16x16x32_bf16(pa[qs], vf1, acc[qs][1], 0, 0, 0);
        }

        // S^T(tile) MFMA (kcur loaded one phase ago) — still high priority
        f32x4 s = __builtin_amdgcn_mfma_f32_16x16x32_bf16(kcur, qfrag, zoff, 0, 0, 0);
        __builtin_amdgcn_s_setprio(0);

        // prefetch V-frags for PV(tile) (consumed next phase)
        vf0 = *(const bf16x8*)(vfp0 + ((size_t)tile << 10));
        vf1 = *(const bf16x8*)(vfp1 + ((size_t)tile << 10));

        // softmax + packed b64 P write
        float p0 = exp2f(s[0]); u32 u0 = as_u(p0) & 0xffff0000u; lps += as_f(u0);
        float p1 = exp2f(s[1]); u32 u1 = as_u(p1) & 0xffff0000u; lps += as_f(u1);
        float p2 = exp2f(s[2]); u32 u2 = as_u(p2) & 0xffff0000u; lps += as_f(u2);
        float p3 = exp2f(s[3]); u32 u3 = as_u(p3) & 0xffff0000u; lps += as_f(u3);
        uint2 pw;
        pw.x = (u0 >> 16) | (u1 & 0xffff0000u);
        pw.y = (u2 >> 16) | (u3 & 0xffff0000u);
        *(uint2*)(Psc + pwoff) = pw;

        barrier_lds_only();
    }

    // ---- final PV(63): parity 1, vf holds jblk of tile 63 ----
    {
        char* Psp = PsA + 8192;
        bf16x8 pa[4];
        #pragma unroll
        for (int qs = 0; qs < 4; ++qs)
            pa[qs] = *(const bf16x8*)(Psp + paoff[qs]);
        #pragma unroll
        for (int qs = 0; qs < 4; ++qs) {
            acc[qs][0] = __builtin_amdgcn_mfma_f32_16x16x32_bf16(pa[qs], vf0, acc[qs][0], 0, 0, 0);
            acc[qs][1] = __builtin_amdgcn_mfma_f32_16x16x32_bf16(pa[qs], vf1, acc[qs][1], 0, 0, 0);
        }
    }

    // ---- l reduction: sum over quads (xor 16, 32), then per-q atomic ----
    lps += __shfl_xor(lps, 16);
    lps += __shfl_xor(lps, 32);
    if (lane < 16) atomicAdd(&lS[(qsub_s << 4) + lane], lps);
    __syncthreads();
    if (t < 64) lS[t] = 1.0f / lS[t];
    const bool isf32 = (dtf != 0);

    // ---- epilogue: 4 chunks of 64 c; combine jq-partials in Dbuf, store ----
    for (int chunk = 0; chunk < 4; ++chunk) {
        __syncthreads();   // Dbuf free; rl ready; Ps reads complete (chunk 0)
        if (jq == 1 && (cq >> 1) == chunk) {
            #pragma unroll
            for (int qs = 0; qs < 4; ++qs)
                #pragma unroll
                for (int cs = 0; cs < 2; ++cs)
                    *(f32x4*)&Dbuf[(((cq & 1) << 5) + (cs << 4) + n16) * 68 +
                                   (qs << 4) + (quad << 2)] = acc[qs][cs];
        }
        __syncthreads();
        if (jq == 0 && (cq >> 1) == chunk) {
            #pragma unroll
            for (int qs = 0; qs < 4; ++qs)
                #pragma unroll
                for (int cs = 0; cs < 2; ++cs) {
                    float* p = &Dbuf[(((cq & 1) << 5) + (cs << 4) + n16) * 68 +
                                     (qs << 4) + (quad << 2)];
                    f32x4 d = *(f32x4*)p;
                    d += acc[qs][cs];
                    *(f32x4*)p = d;
                }
        }
        __syncthreads();
        // store: 1024 threads x 4 q
        const int c_l = t >> 4;
        const int qg  = (t & 15) << 2;
        float4 d  = *(float4*)&Dbuf[c_l * 68 + qg];
        float4 rl = *(float4*)&lS[qg];
        const int c_glob = (chunk << 6) + c_l;
        const size_t ob = (((size_t)(n_g * 256 + c_glob)) << 12) + i0 + qg;
        if (isf32) {
            float4 o = make_float4(d.x * rl.x, d.y * rl.y, d.z * rl.z, d.w * rl.w);
            *(float4*)((float*)out + ob) = o;
        } else {
            union { uint2 v; u16 h[4]; } o;
            o.h[0] = f2bf(d.x * rl.x);
            o.h[1] = f2bf(d.y * rl.y);
            o.h[2] = f2bf(d.z * rl.z);
            o.h[3] = f2bf(d.w * rl.w);
            *(uint2*)((u16*)out + ob) = o.v;
        }
    }
}

extern "C" void kernel_launch(void* const* d_in, const int* in_sizes, int n_in,
                              void* d_out, int out_size, void* d_ws, size_t ws_size,
                              hipStream_t stream)
{
    const void* x  = d_in[0];
    const void* Wq = d_in[1];
    const void* bq = d_in[2];
    const void* Wk = d_in[3];
    const void* bk = d_in[4];
    const void* Wv = d_in[5];
    const void* bv = d_in[6];

    const size_t full_need = (size_t)(4u * 4096u) * (32 + 32 + 256) * 2; // 10 MB
    if (ws_size >= full_need) {
        u16* qws = (u16*)d_ws;
        u16* kws = qws + (size_t)4 * 4096 * 32;
        u16* vws = kws + (size_t)4 * 4096 * 32;
        qkv_proj_mfma<<<dim3(1280), dim3(256), 0, stream>>>(
            x, Wq, bq, Wk, bk, Wv, bv, qws, kws, vws, 0, 2);
        flash_mfma17<<<dim3(256), dim3(1024), 0, stream>>>(
            qws, kws, vws, d_out, x, 0, 2);
    } else {
        u16* qws = (u16*)d_ws;
        u16* kws = qws + (size_t)4096 * 32;
        u16* vws = kws + (size_t)4096 * 32;
        for (int n = 0; n < 4; ++n) {
            qkv_proj_mfma<<<dim3(320), dim3(256), 0, stream>>>(
                x, Wq, bq, Wk, bk, Wv, bv, qws, kws, vws, n, 0);
            flash_mfma17<<<dim3(64), dim3(1024), 0, stream>>>(
                qws, kws, vws, d_out, x, n, 0);
        }
    }
}